// Round 9
// baseline (238.069 us; speedup 1.0000x reference)
//
#include <hip/hip_runtime.h>

#define N_ATOMS 8192
#define DIM 64
#define N_MOL 256
#define KS 16
#define KCH (N_ATOMS / KS)   // 512 k per split
#define BM 64
#define BN 64
#define BK 64
#define NSTEP (KCH / BK)     // 8

typedef __attribute__((ext_vector_type(8))) short short8v;
typedef __attribute__((ext_vector_type(4))) float f32x4;
typedef unsigned short ushort_t;

// f32 -> bf16 RTNE (inputs finite)
__device__ __forceinline__ ushort_t f2bf(float x) {
    unsigned u = __float_as_uint(x);
    u += 0x7fffu + ((u >> 16) & 1u);
    return (ushort_t)(u >> 16);
}

// async global->LDS, 16B per lane, LDS dest = wave-uniform base + lane*16
__device__ __forceinline__ void gload16(const void* gsrc, void* ldst) {
    __builtin_amdgcn_global_load_lds(
        (const __attribute__((address_space(1))) void*)gsrc,
        (__attribute__((address_space(3))) void*)ldst, 16, 0, 0);
}

__device__ __forceinline__ int lower_bound_dev(const int* __restrict__ seg, int val) {
    int lo = 0, hi = N_ATOMS;
    while (lo < hi) {
        int mid = (lo + hi) >> 1;
        if (seg[mid] < val) lo = mid + 1; else hi = mid;
    }
    return lo;
}

// ---- pure streaming convert: Abf = bf16(A). 268 MB R + 134 MB W, HBM-bound. ----
__global__ __launch_bounds__(256) void convert_kernel(
        const float* __restrict__ A, ushort_t* __restrict__ Abf) {
    const size_t total = (size_t)N_ATOMS * N_ATOMS;
    const size_t stride = (size_t)gridDim.x * 256 * 8;
    for (size_t i = ((size_t)blockIdx.x * 256 + threadIdx.x) * 8; i < total; i += stride) {
        float4 a0 = *(const float4*)(A + i);
        float4 a1 = *(const float4*)(A + i + 4);
        short8v vv;
        vv[0] = (short)f2bf(a0.x); vv[1] = (short)f2bf(a0.y);
        vv[2] = (short)f2bf(a0.z); vv[3] = (short)f2bf(a0.w);
        vv[4] = (short)f2bf(a1.x); vv[5] = (short)f2bf(a1.y);
        vv[6] = (short)f2bf(a1.z); vv[7] = (short)f2bf(a1.w);
        *(short8v*)(Abf + i) = vv;
    }
}

// ---- fused linear: v = (FIRST ? embed : vprev); h = relu(W v + b)
// ---- writes vnext = h (f32; mm accumulates A@h on top) and hT (bf16 [DIM][N_ATOMS]).
template <int FIRST>
__global__ __launch_bounds__(256) void fused_linear_kernel(
        const int* __restrict__ fp, const float* __restrict__ table,
        const float* __restrict__ vprev,
        const float* __restrict__ W, const float* __restrict__ b,
        float* __restrict__ vnext, ushort_t* __restrict__ hT) {
    __shared__ float Ws[DIM][DIM + 1];
    __shared__ float vsT[DIM][36];

    const int t = threadIdx.x;
    const int n0 = blockIdx.x * 32;
    for (int i = t; i < DIM * DIM; i += 256) Ws[i >> 6][i & 63] = W[i];
    for (int i = t; i < 32 * DIM; i += 256) {
        const int nl = i >> 6, d = i & 63;
        const size_t n = n0 + nl;
        float val;
        if (FIRST) val = table[(size_t)fp[n] * DIM + d];
        else       val = vprev[n * DIM + d];
        vsT[d][nl] = val;
    }
    __syncthreads();

    const int e = t & 63;
    const int g = t >> 6;
    float acc[8];
    const float be = b[e];
#pragma unroll
    for (int i = 0; i < 8; ++i) acc[i] = be;

    for (int d = 0; d < DIM; ++d) {
        const float w = Ws[e][d];
        const float4* vp = (const float4*)&vsT[d][g * 8];
        float4 x0 = vp[0], x1 = vp[1];
        acc[0] += w * x0.x; acc[1] += w * x0.y; acc[2] += w * x0.z; acc[3] += w * x0.w;
        acc[4] += w * x1.x; acc[5] += w * x1.y; acc[6] += w * x1.z; acc[7] += w * x1.w;
    }

    ushort_t hb[8];
#pragma unroll
    for (int i = 0; i < 8; ++i) {
        float hv = acc[i] > 0.f ? acc[i] : 0.f;
        vnext[(size_t)(n0 + g * 8 + i) * DIM + e] = hv;
        hb[i] = f2bf(hv);
    }
    *(short8v*)(hT + (size_t)e * N_ATOMS + n0 + g * 8) = *(short8v*)&hb[0];
}

// ---- vnext += Abf[rows, ksplit] @ h  — BM=64, 32 KB LDS => 5 blocks/CU.
// grid (N_ATOMS/BM, KS), 256 threads = 4 waves; wave w: rows w*16..+16, cols 0..64.
// LDS: tile[row][slot], slot s (8 bf16 = 16B) at s ^ (row&7); linear dest +
// inverse-swizzled global source (rule #21).
__global__ __launch_bounds__(256) void matmul_mfma_kernel(
        const ushort_t* __restrict__ Abf, const ushort_t* __restrict__ hT,
        float* __restrict__ vnext) {
    __shared__ ushort_t Asw[2][BM * BK];   // 2 x 8 KB
    __shared__ ushort_t Bsw[2][BN * BK];   // 2 x 8 KB

    const int t  = threadIdx.x;
    const int w  = t >> 6;
    const int l  = t & 63;
    const int lm = l & 15;
    const int lq = l >> 4;
    const int r0 = blockIdx.x * BM;
    const size_t kc0 = (size_t)blockIdx.y * KCH;

    auto stage = [&](int bi, size_t kb) {
#pragma unroll
        for (int q = 0; q < 2; ++q) {
            const int i = q * 256 + t;
            const int r = i >> 3, s = i & 7;
            gload16(Abf + (size_t)(r0 + r) * N_ATOMS + kb + ((s ^ (r & 7)) << 3),
                    &Asw[bi][(q * 256 + w * 64) * 8]);
        }
#pragma unroll
        for (int q = 0; q < 2; ++q) {
            const int i = q * 256 + t;
            const int r = i >> 3, s = i & 7;
            gload16(hT + (size_t)r * N_ATOMS + kb + ((s ^ (r & 7)) << 3),
                    &Bsw[bi][(q * 256 + w * 64) * 8]);
        }
    };

    f32x4 acc[4];
#pragma unroll
    for (int n = 0; n < 4; ++n) acc[n] = (f32x4){0.f, 0.f, 0.f, 0.f};

    stage(0, kc0);
    __syncthreads();

    for (int ks = 0; ks < NSTEP; ++ks) {
        const int bi = ks & 1;
        if (ks + 1 < NSTEP) stage(bi ^ 1, kc0 + (size_t)(ks + 1) * BK);
#pragma unroll
        for (int kki = 0; kki < 2; ++kki) {
            const int sx = ((kki * 4 + lq) ^ (lm & 7)) << 3;
            const int ra = w * 16 + lm;
            short8v a0 = *(const short8v*)&Asw[bi][ra * BK + sx];
            short8v b0 = *(const short8v*)&Bsw[bi][(lm)      * BK + sx];
            short8v b1 = *(const short8v*)&Bsw[bi][(lm + 16) * BK + sx];
            short8v b2 = *(const short8v*)&Bsw[bi][(lm + 32) * BK + sx];
            short8v b3 = *(const short8v*)&Bsw[bi][(lm + 48) * BK + sx];
            acc[0] = __builtin_amdgcn_mfma_f32_16x16x32_bf16(a0, b0, acc[0], 0, 0, 0);
            acc[1] = __builtin_amdgcn_mfma_f32_16x16x32_bf16(a0, b1, acc[1], 0, 0, 0);
            acc[2] = __builtin_amdgcn_mfma_f32_16x16x32_bf16(a0, b2, acc[2], 0, 0, 0);
            acc[3] = __builtin_amdgcn_mfma_f32_16x16x32_bf16(a0, b3, acc[3], 0, 0, 0);
        }
        __syncthreads();
    }

    // C/D layout: col = lane&15, row = (lane>>4)*4 + reg  [m89 verified]
    const int rb = r0 + w * 16 + lq * 4;
#pragma unroll
    for (int j = 0; j < 4; ++j) {
        float* vp = vnext + (size_t)(rb + j) * DIM + lm;
#pragma unroll
        for (int n = 0; n < 4; ++n) atomicAdd(vp + n * 16, acc[n][j]);
    }
}

// ------ segment sum: out[m][d] = sum_{n: seg[n]==m} v[n][d] ------
__global__ __launch_bounds__(256) void segsum_kernel(
        const float* __restrict__ v, const int* __restrict__ seg,
        float* __restrict__ out) {
    __shared__ float sm[4][DIM];
    const int m = blockIdx.x;
    const int d = threadIdx.x & 63;
    const int g = threadIdx.x >> 6;
    const int lo = lower_bound_dev(seg, m);
    const int hi = lower_bound_dev(seg, m + 1);
    float acc = 0.f;
    for (int n = lo + g; n < hi; n += 4) acc += v[(size_t)n * DIM + d];
    sm[g][d] = acc;
    __syncthreads();
    if (g == 0) out[(size_t)m * DIM + d] = sm[0][d] + sm[1][d] + sm[2][d] + sm[3][d];
}

extern "C" void kernel_launch(void* const* d_in, const int* in_sizes, int n_in,
                              void* d_out, int out_size, void* d_ws, size_t ws_size,
                              hipStream_t stream) {
    const int*   fp    = (const int*)d_in[0];
    const float* A     = (const float*)d_in[1];
    const int*   seg   = (const int*)d_in[2];
    const float* table = (const float*)d_in[3];
    const float* W     = (const float*)d_in[4];
    const float* b     = (const float*)d_in[5];
    float* out = (float*)d_out;

    float*    vA  = (float*)d_ws;                                  // 2 MB
    float*    vB  = vA + (size_t)N_ATOMS * DIM;                    // 2 MB
    ushort_t* hT  = (ushort_t*)(vB + (size_t)N_ATOMS * DIM);       // 1 MB
    ushort_t* Abf = hT + (size_t)DIM * N_ATOMS;                    // 134 MB

    dim3 mmgrid(N_ATOMS / BM, KS);

    // one-time stream convert (HBM-bound, ~65 us)
    convert_kernel<<<2048, 256, 0, stream>>>(A, Abf);
    // layer 0: vA = h0, vA += A@h0
    fused_linear_kernel<1><<<N_ATOMS / 32, 256, 0, stream>>>(
        fp, table, nullptr, W, b, vA, hT);
    matmul_mfma_kernel<<<mmgrid, 256, 0, stream>>>(Abf, hT, vA);
    // layer 1
    fused_linear_kernel<0><<<N_ATOMS / 32, 256, 0, stream>>>(
        fp, table, vA, W + DIM * DIM, b + DIM, vB, hT);
    matmul_mfma_kernel<<<mmgrid, 256, 0, stream>>>(Abf, hT, vB);
    // layer 2
    fused_linear_kernel<0><<<N_ATOMS / 32, 256, 0, stream>>>(
        fp, table, vB, W + 2 * DIM * DIM, b + 2 * DIM, vA, hT);
    matmul_mfma_kernel<<<mmgrid, 256, 0, stream>>>(Abf, hT, vA);
    // pooled output
    segsum_kernel<<<N_MOL, 256, 0, stream>>>(vA, seg, out);
}

// Round 10
// 226.476 us; speedup vs baseline: 1.0512x; 1.0512x over previous
//
#include <hip/hip_runtime.h>

#define N_ATOMS 8192
#define DIM 64
#define N_MOL 256
#define KS 16
#define KCH (N_ATOMS / KS)   // 512 k per split
#define BM 64
#define BN 64
#define BK 64
#define NSTEP (KCH / BK)     // 8

typedef __attribute__((ext_vector_type(8))) short short8v;
typedef __attribute__((ext_vector_type(4))) float f32x4;
typedef unsigned short ushort_t;

// f32 -> bf16 RTNE (inputs finite)
__device__ __forceinline__ ushort_t f2bf(float x) {
    unsigned u = __float_as_uint(x);
    u += 0x7fffu + ((u >> 16) & 1u);
    return (ushort_t)(u >> 16);
}

// async global->LDS, 16B per lane, LDS dest = wave-uniform base + lane*16
__device__ __forceinline__ void gload16(const void* gsrc, void* ldst) {
    __builtin_amdgcn_global_load_lds(
        (const __attribute__((address_space(1))) void*)gsrc,
        (__attribute__((address_space(3))) void*)ldst, 16, 0, 0);
}

__device__ __forceinline__ int lower_bound_dev(const int* __restrict__ seg, int val) {
    int lo = 0, hi = N_ATOMS;
    while (lo < hi) {
        int mid = (lo + hi) >> 1;
        if (seg[mid] < val) lo = mid + 1; else hi = mid;
    }
    return lo;
}

// ---- pure streaming convert: Abf = bf16(A). 268 MB R + 134 MB W, HBM-bound. ----
__global__ __launch_bounds__(256) void convert_kernel(
        const float* __restrict__ A, ushort_t* __restrict__ Abf) {
    const size_t total = (size_t)N_ATOMS * N_ATOMS;
    const size_t stride = (size_t)gridDim.x * 256 * 8;
    for (size_t i = ((size_t)blockIdx.x * 256 + threadIdx.x) * 8; i < total; i += stride) {
        float4 a0 = *(const float4*)(A + i);
        float4 a1 = *(const float4*)(A + i + 4);
        short8v vv;
        vv[0] = (short)f2bf(a0.x); vv[1] = (short)f2bf(a0.y);
        vv[2] = (short)f2bf(a0.z); vv[3] = (short)f2bf(a0.w);
        vv[4] = (short)f2bf(a1.x); vv[5] = (short)f2bf(a1.y);
        vv[6] = (short)f2bf(a1.z); vv[7] = (short)f2bf(a1.w);
        *(short8v*)(Abf + i) = vv;
    }
}

// ---- fused linear: v = (FIRST ? embed : vprev); h = relu(W v + b)
// ---- writes vnext = h (f32; mm accumulates A@h on top) and hT (bf16 [DIM][N_ATOMS]).
template <int FIRST>
__global__ __launch_bounds__(256) void fused_linear_kernel(
        const int* __restrict__ fp, const float* __restrict__ table,
        const float* __restrict__ vprev,
        const float* __restrict__ W, const float* __restrict__ b,
        float* __restrict__ vnext, ushort_t* __restrict__ hT) {
    __shared__ float Ws[DIM][DIM + 1];
    __shared__ float vsT[DIM][36];

    const int t = threadIdx.x;
    const int n0 = blockIdx.x * 32;
    for (int i = t; i < DIM * DIM; i += 256) Ws[i >> 6][i & 63] = W[i];
    for (int i = t; i < 32 * DIM; i += 256) {
        const int nl = i >> 6, d = i & 63;
        const size_t n = n0 + nl;
        float val;
        if (FIRST) val = table[(size_t)fp[n] * DIM + d];
        else       val = vprev[n * DIM + d];
        vsT[d][nl] = val;
    }
    __syncthreads();

    const int e = t & 63;
    const int g = t >> 6;
    float acc[8];
    const float be = b[e];
#pragma unroll
    for (int i = 0; i < 8; ++i) acc[i] = be;

    for (int d = 0; d < DIM; ++d) {
        const float w = Ws[e][d];
        const float4* vp = (const float4*)&vsT[d][g * 8];
        float4 x0 = vp[0], x1 = vp[1];
        acc[0] += w * x0.x; acc[1] += w * x0.y; acc[2] += w * x0.z; acc[3] += w * x0.w;
        acc[4] += w * x1.x; acc[5] += w * x1.y; acc[6] += w * x1.z; acc[7] += w * x1.w;
    }

    ushort_t hb[8];
#pragma unroll
    for (int i = 0; i < 8; ++i) {
        float hv = acc[i] > 0.f ? acc[i] : 0.f;
        vnext[(size_t)(n0 + g * 8 + i) * DIM + e] = hv;
        hb[i] = f2bf(hv);
    }
    *(short8v*)(hT + (size_t)e * N_ATOMS + n0 + g * 8) = *(short8v*)&hb[0];
}

// ---- vnext += Abf[rows, ksplit] @ h  — BM=64, counted-vmcnt pipeline (T3/T4).
// grid (N_ATOMS/BM, KS), 256 threads = 4 waves; wave w: rows w*16..+16, cols 0..64.
// LDS: tile[row][slot], slot s (16B) at s ^ (row&7); linear dest + inverse-swizzled
// global source (rule #21). Schedule per K-step:
//   stage(next tile: 4 gload_lds) ; s_waitcnt vmcnt(4) ; s_barrier   (cur ready)
//   ds_read + MFMA(cur) ; s_barrier                                  (reads done)
// Next-tile loads stay in flight across the MFMA phase (never vmcnt(0) mid-loop).
__global__ __launch_bounds__(256) void matmul_mfma_kernel(
        const ushort_t* __restrict__ Abf, const ushort_t* __restrict__ hT,
        float* __restrict__ vnext) {
    __shared__ ushort_t Asw[2][BM * BK];   // 2 x 8 KB
    __shared__ ushort_t Bsw[2][BN * BK];   // 2 x 8 KB

    const int t  = threadIdx.x;
    const int w  = t >> 6;
    const int l  = t & 63;
    const int lm = l & 15;
    const int lq = l >> 4;
    const int r0 = blockIdx.x * BM;
    const size_t kc0 = (size_t)blockIdx.y * KCH;

    auto stage = [&](int bi, size_t kb) {
#pragma unroll
        for (int q = 0; q < 2; ++q) {
            const int i = q * 256 + t;
            const int r = i >> 3, s = i & 7;
            gload16(Abf + (size_t)(r0 + r) * N_ATOMS + kb + ((s ^ (r & 7)) << 3),
                    &Asw[bi][(q * 256 + w * 64) * 8]);
        }
#pragma unroll
        for (int q = 0; q < 2; ++q) {
            const int i = q * 256 + t;
            const int r = i >> 3, s = i & 7;
            gload16(hT + (size_t)r * N_ATOMS + kb + ((s ^ (r & 7)) << 3),
                    &Bsw[bi][(q * 256 + w * 64) * 8]);
        }
    };

    f32x4 acc[4];
#pragma unroll
    for (int n = 0; n < 4; ++n) acc[n] = (f32x4){0.f, 0.f, 0.f, 0.f};

    stage(0, kc0);   // 4 loads in flight

    for (int ks = 0; ks < NSTEP; ++ks) {
        const int bi = ks & 1;
        if (ks + 1 < NSTEP) {
            stage(bi ^ 1, kc0 + (size_t)(ks + 1) * BK);   // +4 newest
            asm volatile("s_waitcnt vmcnt(4)" ::: "memory");  // cur's 4 done
        } else {
            asm volatile("s_waitcnt vmcnt(0)" ::: "memory");
        }
        __builtin_amdgcn_s_barrier();                     // B1: buf[bi] readable
        asm volatile("" ::: "memory");
#pragma unroll
        for (int kki = 0; kki < 2; ++kki) {
            const int sx = ((kki * 4 + lq) ^ (lm & 7)) << 3;
            const int ra = w * 16 + lm;
            short8v a0 = *(const short8v*)&Asw[bi][ra * BK + sx];
            short8v b0 = *(const short8v*)&Bsw[bi][(lm)      * BK + sx];
            short8v b1 = *(const short8v*)&Bsw[bi][(lm + 16) * BK + sx];
            short8v b2 = *(const short8v*)&Bsw[bi][(lm + 32) * BK + sx];
            short8v b3 = *(const short8v*)&Bsw[bi][(lm + 48) * BK + sx];
            acc[0] = __builtin_amdgcn_mfma_f32_16x16x32_bf16(a0, b0, acc[0], 0, 0, 0);
            acc[1] = __builtin_amdgcn_mfma_f32_16x16x32_bf16(a0, b1, acc[1], 0, 0, 0);
            acc[2] = __builtin_amdgcn_mfma_f32_16x16x32_bf16(a0, b2, acc[2], 0, 0, 0);
            acc[3] = __builtin_amdgcn_mfma_f32_16x16x32_bf16(a0, b3, acc[3], 0, 0, 0);
        }
        asm volatile("" ::: "memory");
        __builtin_amdgcn_s_barrier();                     // B2: reads of buf[bi] done
        asm volatile("" ::: "memory");
    }

    // C/D layout: col = lane&15, row = (lane>>4)*4 + reg  [m89 verified]
    const int rb = r0 + w * 16 + lq * 4;
#pragma unroll
    for (int j = 0; j < 4; ++j) {
        float* vp = vnext + (size_t)(rb + j) * DIM + lm;
#pragma unroll
        for (int n = 0; n < 4; ++n) atomicAdd(vp + n * 16, acc[n][j]);
    }
}

// ------ segment sum: out[m][d] = sum_{n: seg[n]==m} v[n][d] ------
__global__ __launch_bounds__(256) void segsum_kernel(
        const float* __restrict__ v, const int* __restrict__ seg,
        float* __restrict__ out) {
    __shared__ float sm[4][DIM];
    const int m = blockIdx.x;
    const int d = threadIdx.x & 63;
    const int g = threadIdx.x >> 6;
    const int lo = lower_bound_dev(seg, m);
    const int hi = lower_bound_dev(seg, m + 1);
    float acc = 0.f;
    for (int n = lo + g; n < hi; n += 4) acc += v[(size_t)n * DIM + d];
    sm[g][d] = acc;
    __syncthreads();
    if (g == 0) out[(size_t)m * DIM + d] = sm[0][d] + sm[1][d] + sm[2][d] + sm[3][d];
}

extern "C" void kernel_launch(void* const* d_in, const int* in_sizes, int n_in,
                              void* d_out, int out_size, void* d_ws, size_t ws_size,
                              hipStream_t stream) {
    const int*   fp    = (const int*)d_in[0];
    const float* A     = (const float*)d_in[1];
    const int*   seg   = (const int*)d_in[2];
    const float* table = (const float*)d_in[3];
    const float* W     = (const float*)d_in[4];
    const float* b     = (const float*)d_in[5];
    float* out = (float*)d_out;

    float*    vA  = (float*)d_ws;                                  // 2 MB
    float*    vB  = vA + (size_t)N_ATOMS * DIM;                    // 2 MB
    ushort_t* hT  = (ushort_t*)(vB + (size_t)N_ATOMS * DIM);       // 1 MB
    ushort_t* Abf = hT + (size_t)DIM * N_ATOMS;                    // 134 MB

    dim3 mmgrid(N_ATOMS / BM, KS);

    // one-time stream convert (HBM-bound, ~65 us)
    convert_kernel<<<2048, 256, 0, stream>>>(A, Abf);
    // layer 0: vA = h0, vA += A@h0
    fused_linear_kernel<1><<<N_ATOMS / 32, 256, 0, stream>>>(
        fp, table, nullptr, W, b, vA, hT);
    matmul_mfma_kernel<<<mmgrid, 256, 0, stream>>>(Abf, hT, vA);
    // layer 1
    fused_linear_kernel<0><<<N_ATOMS / 32, 256, 0, stream>>>(
        fp, table, vA, W + DIM * DIM, b + DIM, vB, hT);
    matmul_mfma_kernel<<<mmgrid, 256, 0, stream>>>(Abf, hT, vB);
    // layer 2
    fused_linear_kernel<0><<<N_ATOMS / 32, 256, 0, stream>>>(
        fp, table, vB, W + 2 * DIM * DIM, b + 2 * DIM, vA, hT);
    matmul_mfma_kernel<<<mmgrid, 256, 0, stream>>>(Abf, hT, vA);
    // pooled output
    segsum_kernel<<<N_MOL, 256, 0, stream>>>(vA, seg, out);
}